// Round 9
// baseline (122.128 us; speedup 1.0000x reference)
//
#include <hip/hip_runtime.h>
#include <math.h>

// ---- Problem constants -----------------------------------------------------
#define NQ        12
#define NPS       14
#define NPATCH    196
#define NB        4
#define NCLS      1000
#define FEATDIM   2352           // 196*12
#define SCALE_F   0.28867513459481287f  // 1/sqrt(12)

// ---- Layouts ----------------------------------------------------------------
// 128-thread block (2 waves), 32 amps/thread. Frozen: q2 at amp bit0 (w=1),
// q3 at amp bit1 (w=2) in EVERY layout -> relayout reads are 4-word contiguous
// (b128). Storage stride 36 words (144 B, 16B-aligned; 4l mod 32 banks uniform).
// PRa[L][k] = qubit at amp bit k; PTa[L][m] = qubit at tid bit m (m6 = wave).
// All 8 transitions verified: reader lane-bit weights mod 32 == {4,8,16,0,0,0}
// (uniform 8 words/bank) and all offsets multiple of 4 words (16B alignment).
constexpr int PRa[8][5] = {
    {2,3,0,1, 4},   // S1 trio q0,q1,q4
    {2,3,4,5, 6},   // S2 trio q4,q5,q6
    {2,3,5,6, 7},   // S3 trio q5,q6,q7
    {2,3,0,4, 6},   // S4 trio q0,q4,q6
    {2,3,8,9,10},   // S5 trio q8,q9,q10
    {2,3,9,10,11},  // S6 trio q9,q10,q11
    {2,3,0,8,10},   // S7 trio q0,q8,q10
    {2,3,1,5, 9},   // S8 trio q1,q5,q9
};
constexpr int PTa[8][7] = {
    {5,6,7,8,9,10,11},   // S1 | wave q11
    {7,0,1,8,9,10,11},   // S2 | wave q11
    {0,1,4,8,9,10,11},   // S3 | wave q11
    {8,9,10,1,5,7,11},   // S4 | wave q11
    {4,0,1,5,6,7,11},    // S5 | wave q11
    {0,1,8,5,6,7,4},     // S6 | wave q4
    {1,5,9,6,7,11,4},    // S7 | wave q4
    {6,0,11,7,8,10,4},   // S8 | wave q4
};
// wave qubit changes only at T56 (TI=4) and T81 (TI=7) -> full barriers there;
// all other transitions are intra-wave (own-region only; DS in-order per wave).
constexpr bool BARa[8] = {false,false,false,false,true,false,false,true};

// weight (words) of qubit q in layout X storage (addr = 36*t + r)
constexpr int cwgt(int X, int q) {
    for (int k = 0; k < 5; ++k) if (PRa[X][k] == q) return 1 << k;
    for (int m = 0; m < 7; ++m) if (PTa[X][m] == q) return 36 << m;
    return 0;
}
// imm offset for reader's amp bits 2..4 value a (bits 0,1 are the in-float4 lane)
constexpr int rimmB(int X, int Y, int a) {
    int s = 0;
    for (int j = 0; j < 3; ++j)
        if ((a >> j) & 1) s += cwgt(X, PRa[Y][2 + j]);
    return s;
}

__device__ __forceinline__ void wait_lgkm() {
    __asm__ __volatile__("s_waitcnt lgkmcnt(0)" ::: "memory");
}

template<int TI>
__device__ __forceinline__ void relayoutB(float amp[32], float* lds, int tid) {
    constexpr int X = TI, Y = (TI + 1) & 7;
    float4* dst = (float4*)(lds + 36 * tid);
    #pragma unroll
    for (int k = 0; k < 8; ++k)
        dst[k] = make_float4(amp[4*k], amp[4*k+1], amp[4*k+2], amp[4*k+3]);
    if (BARa[TI]) __syncthreads(); else wait_lgkm();
    int base = 0;
    #pragma unroll
    for (int j = 0; j < 7; ++j)
        base += ((tid >> j) & 1) ? cwgt(X, PTa[Y][j]) : 0;
    #pragma unroll
    for (int a = 0; a < 8; ++a) {
        float4 v = *(const float4*)(lds + base + rimmB(X, Y, a));
        amp[4*a+0] = v.x; amp[4*a+1] = v.y; amp[4*a+2] = v.z; amp[4*a+3] = v.w;
    }
    if (BARa[TI]) __syncthreads();
}

// RBS gate on amp bits MI (first qubit w1) / MJ (second qubit w2).
// Half-angle form: gc = 0.5*cos(2t), gs = 0.5*sin(2t).
template<int MI, int MJ>
__device__ __forceinline__ void apply_gate(float amp[32], float gc, float gs) {
    #pragma unroll
    for (int m = 0; m < 32; ++m) {
        if (m & (MI | MJ)) continue;
        float a0 = amp[m], a1 = amp[m | MJ], a2 = amp[m | MI], a3 = amp[m | MI | MJ];
        float p  = a0 + a1, q  = a0 - a1;
        float p2 = a2 + a3, q2 = a2 - a3;
        float t1 = 0.5f * p  + gc * q  - gs * q2;
        float t2 = 0.5f * p2 + gc * q2 + gs * q;
        amp[m]           = t1;
        amp[m | MJ]      = p  - t1;
        amp[m | MI]      = t2;
        amp[m | MI | MJ] = p2 - t2;
    }
}

// ---- DPP wave-wide sum (result valid in lane 63), pure VALU ----------------
template<int CTRL>
__device__ __forceinline__ float dppadd(float x) {
    int s = __builtin_amdgcn_update_dpp(0, __float_as_int(x), CTRL, 0xf, 0xf, true);
    return x + __int_as_float(s);
}
__device__ __forceinline__ float wave_sum(float x) {
    x = dppadd<0x111>(x);   // row_shr:1
    x = dppadd<0x112>(x);   // row_shr:2
    x = dppadd<0x114>(x);   // row_shr:4
    x = dppadd<0x118>(x);   // row_shr:8
    x = dppadd<0x142>(x);   // row_bcast:15
    x = dppadd<0x143>(x);   // row_bcast:31
    return x;
}

// ---- Kernel: fused projection + quantum circuit ----------------------------
// grid (196, 4, 3), block 128 (two waves). LDS ~18.9 KB.
__global__ __launch_bounds__(128, 4) void qcirc_kernel(
    const float* __restrict__ x,      // (4,3,224,224)
    const float* __restrict__ Wp,     // (12,256)
    const float* __restrict__ bproj,  // (12,)
    const float* __restrict__ qp,
    const float* __restrict__ kp,
    const float* __restrict__ vp,
    float* __restrict__ qkv)          // (3,784,12)
{
    __shared__ __align__(16) float lds[4608];   // 36*128 words
    __shared__ float chs[NQ], shs[NQ];
    __shared__ float gC[40], gS[40];
    __shared__ float red2[2][12];

    const int tid = threadIdx.x;
    const int p = blockIdx.x, b = blockIdx.y, c = blockIdx.z;
    const int bp = b * NPATCH + p;
    const float* params = (c == 0) ? qp : (c == 1) ? kp : vp;
    const int lane = tid & 63, wv = tid >> 6;

    // ---- projection: 2 pixels/thread, DPP wave sums ----
    float part[NQ];
    #pragma unroll
    for (int q = 0; q < NQ; ++q) part[q] = 0.0f;
    {
        int py = p / NPS, px = p % NPS;
        const float* xb = x + (size_t)b * 3 * 224 * 224;
        #pragma unroll
        for (int k = 0; k < 2; ++k) {
            int pix = tid + 128 * k;
            int off = (py * 16 + (pix >> 4)) * 224 + px * 16 + (pix & 15);
            float v = (xb[off] + xb[off + 50176] + xb[off + 100352]) * (1.0f / 3.0f);
            #pragma unroll
            for (int q = 0; q < NQ; ++q) part[q] += v * Wp[q * 256 + pix];
        }
    }
    if (tid < 40) {
        int l = tid / 20, g = tid - l * 20;
        float th = params[l * 32 + g];
        gC[tid] = 0.5f * cosf(2.0f * th);
        gS[tid] = 0.5f * sinf(2.0f * th);
    }
    #pragma unroll
    for (int q = 0; q < NQ; ++q) part[q] = wave_sum(part[q]);
    if (lane == 63) {
        #pragma unroll
        for (int q = 0; q < NQ; ++q) red2[wv][q] = part[q];
    }
    __syncthreads();
    if (tid < NQ) {
        float h = 0.5f * (red2[0][tid] + red2[1][tid] + bproj[tid]);
        chs[tid] = cosf(h); shs[tid] = sinf(h);
    }
    __syncthreads();

    // ---- init in S1: amp b0=q2 b1=q3 b2=q0 b3=q1 b4=q4;
    //      tid t0=q5 t1=q6 t2=q7 t3=q8 t4=q9 t5=q10 | wave t6=q11 ----
    float amp[32];
    {
        float hi = ((tid &  1) ? shs[5]  : chs[5])  *
                   ((tid &  2) ? shs[6]  : chs[6])  *
                   ((tid &  4) ? shs[7]  : chs[7])  *
                   ((tid &  8) ? shs[8]  : chs[8])  *
                   ((tid & 16) ? shs[9]  : chs[9])  *
                   ((tid & 32) ? shs[10] : chs[10]) *
                   ((tid & 64) ? shs[11] : chs[11]);
        float pA[8], pB[4];
        #pragma unroll
        for (int i = 0; i < 8; ++i)
            pA[i] = ((i & 1) ? shs[2] : chs[2]) * ((i & 2) ? shs[3] : chs[3]) *
                    ((i & 4) ? shs[0] : chs[0]);
        #pragma unroll
        for (int i = 0; i < 4; ++i)
            pB[i] = ((i & 1) ? shs[1] : chs[1]) * ((i & 2) ? shs[4] : chs[4]);
        #pragma unroll
        for (int r = 0; r < 32; ++r) amp[r] = pA[r & 7] * pB[r >> 3] * hi;
    }

    // ---- 2 layers x 8 runs; 15 relayouts (13 barrier-free); schedule
    //      verified against all 12 per-qubit gate chains ----
    #pragma unroll 1
    for (int l = 0; l < 2; ++l) {
        const int bb = l * 20;
        // S1 trio(q0,q1,q4): p0(0,1) p1(2,3) p6(0,2) p7(1,3)
        apply_gate<4, 8>(amp, gC[bb+0], gS[bb+0]);
        apply_gate<1, 2>(amp, gC[bb+1], gS[bb+1]);
        apply_gate<4, 1>(amp, gC[bb+6], gS[bb+6]);
        apply_gate<8, 2>(amp, gC[bb+7], gS[bb+7]);
        relayoutB<0>(amp, lds, tid);
        // S2 trio(q4,q5,q6): p2(4,5)
        apply_gate<4, 8>(amp, gC[bb+2], gS[bb+2]);
        relayoutB<1>(amp, lds, tid);
        // S3 trio(q5,q6,q7): p3(6,7) p9(5,7) p15(3,7)
        apply_gate<8,16>(amp, gC[bb+3],  gS[bb+3]);
        apply_gate<4,16>(amp, gC[bb+9],  gS[bb+9]);
        apply_gate<2,16>(amp, gC[bb+15], gS[bb+15]);
        relayoutB<2>(amp, lds, tid);
        // S4 trio(q0,q4,q6): p8(4,6) p12(0,4) p14(2,6)
        apply_gate<8,16>(amp, gC[bb+8],  gS[bb+8]);
        apply_gate<4, 8>(amp, gC[bb+12], gS[bb+12]);
        apply_gate<1,16>(amp, gC[bb+14], gS[bb+14]);
        relayoutB<3>(amp, lds, tid);
        // S5 trio(q8,q9,q10): p4(8,9)
        apply_gate<4, 8>(amp, gC[bb+4], gS[bb+4]);
        relayoutB<4>(amp, lds, tid);
        // S6 trio(q9,q10,q11): p5(10,11) p11(9,11) p19(3,11)
        apply_gate<8,16>(amp, gC[bb+5],  gS[bb+5]);
        apply_gate<4,16>(amp, gC[bb+11], gS[bb+11]);
        apply_gate<2,16>(amp, gC[bb+19], gS[bb+19]);
        relayoutB<5>(amp, lds, tid);
        // S7 trio(q0,q8,q10): p10(8,10) p16(0,8) p18(2,10)
        apply_gate<8,16>(amp, gC[bb+10], gS[bb+10]);
        apply_gate<4, 8>(amp, gC[bb+16], gS[bb+16]);
        apply_gate<1,16>(amp, gC[bb+18], gS[bb+18]);
        relayoutB<6>(amp, lds, tid);
        // S8 trio(q1,q5,q9): p13(1,5) p17(1,9)
        apply_gate<4, 8>(amp, gC[bb+13], gS[bb+13]);
        apply_gate<4,16>(amp, gC[bb+17], gS[bb+17]);
        if (l == 0) relayoutB<7>(amp, lds, tid);
    }

    // ---- expvals in S8: amp b0=q2 b1=q3 b2=q1 b3=q5 b4=q9;
    //      tid t0=q6 t1=q0 t2=q11 t3=q7 t4=q8 t5=q10 | wave t6=q4 ----
    float T, Sq2, Sq3, Sq1, Sq5, Sq9;
    {
        float t1[16]; Sq2 = 0.0f;
        #pragma unroll
        for (int i = 0; i < 16; ++i) {
            float e = amp[2*i] * amp[2*i], o = amp[2*i+1] * amp[2*i+1];
            t1[i] = e + o; Sq2 += e - o;
        }
        float t2[8]; Sq3 = 0.0f;
        #pragma unroll
        for (int i = 0; i < 8; ++i) { t2[i] = t1[2*i] + t1[2*i+1]; Sq3 += t1[2*i] - t1[2*i+1]; }
        float t3[4]; Sq1 = 0.0f;
        #pragma unroll
        for (int i = 0; i < 4; ++i) { t3[i] = t2[2*i] + t2[2*i+1]; Sq1 += t2[2*i] - t2[2*i+1]; }
        float t4[2]; Sq5 = 0.0f;
        #pragma unroll
        for (int i = 0; i < 2; ++i) { t4[i] = t3[2*i] + t3[2*i+1]; Sq5 += t3[2*i] - t3[2*i+1]; }
        T = t4[0] + t4[1]; Sq9 = t4[0] - t4[1];
    }
    // lane-signed totals then DPP wave sums
    float Vq6  = (tid &  1) ? -T : T;
    float Vq0  = (tid &  2) ? -T : T;
    float Vq11 = (tid &  4) ? -T : T;
    float Vq7  = (tid &  8) ? -T : T;
    float Vq8  = (tid & 16) ? -T : T;
    float Vq10 = (tid & 32) ? -T : T;
    T    = wave_sum(T);
    Vq6  = wave_sum(Vq6);  Vq0  = wave_sum(Vq0);  Vq11 = wave_sum(Vq11);
    Vq7  = wave_sum(Vq7);  Vq8  = wave_sum(Vq8);  Vq10 = wave_sum(Vq10);
    Sq2  = wave_sum(Sq2);  Sq3  = wave_sum(Sq3);  Sq1  = wave_sum(Sq1);
    Sq5  = wave_sum(Sq5);  Sq9  = wave_sum(Sq9);
    if (lane == 63) {
        red2[wv][0]  = Vq0;  red2[wv][1]  = Sq1;  red2[wv][2]  = Sq2;
        red2[wv][3]  = Sq3;  red2[wv][4]  = T;    red2[wv][5]  = Sq5;
        red2[wv][6]  = Vq6;  red2[wv][7]  = Vq7;  red2[wv][8]  = Vq8;
        red2[wv][9]  = Sq9;  red2[wv][10] = Vq10; red2[wv][11] = Vq11;
    }
    __syncthreads();
    if (tid < NQ) {
        float v1 = red2[1][tid];
        float s = red2[0][tid] + ((tid == 4) ? -v1 : v1);   // wave bit = q4
        qkv[((size_t)c * (NB * NPATCH) + bp) * NQ + tid] = s;
    }
}

// ---- Kernel: attention ------------------------------------------------------
__global__ __launch_bounds__(256) void attn_kernel(
    const float* __restrict__ qkv,    // (3,784,12)
    float* __restrict__ outb)         // (4,2352)
{
    int tid = threadIdx.x;
    int qp = blockIdx.x, b = blockIdx.y;
    const float* Q = qkv;
    const float* K = qkv + NB * NPATCH * NQ;
    const float* V = qkv + 2 * NB * NPATCH * NQ;

    __shared__ float redm[4], reds[4], redv[4][NQ];

    float4 q0 = ((const float4*)(Q + (b * NPATCH + qp) * NQ))[0];
    float4 q1 = ((const float4*)(Q + (b * NPATCH + qp) * NQ))[1];
    float4 q2 = ((const float4*)(Q + (b * NPATCH + qp) * NQ))[2];

    float score = -1e30f;
    float4 v0, v1, v2;
    if (tid < NPATCH) {
        const float4* K4 = (const float4*)(K + (b * NPATCH + tid) * NQ);
        float4 k0 = K4[0], k1 = K4[1], k2 = K4[2];
        float s = q0.x*k0.x + q0.y*k0.y + q0.z*k0.z + q0.w*k0.w
                + q1.x*k1.x + q1.y*k1.y + q1.z*k1.z + q1.w*k1.w
                + q2.x*k2.x + q2.y*k2.y + q2.z*k2.z + q2.w*k2.w;
        score = s * SCALE_F;
        const float4* V4 = (const float4*)(V + (b * NPATCH + tid) * NQ);
        v0 = V4[0]; v1 = V4[1]; v2 = V4[2];
    }
    float m = score;
    #pragma unroll
    for (int o = 32; o > 0; o >>= 1) m = fmaxf(m, __shfl_down(m, o));
    int lane = tid & 63, wv = tid >> 6;
    if (lane == 0) redm[wv] = m;
    __syncthreads();
    float maxv = fmaxf(fmaxf(redm[0], redm[1]), fmaxf(redm[2], redm[3]));

    float w = (tid < NPATCH) ? expf(score - maxv) : 0.0f;
    float sm = w;
    #pragma unroll
    for (int o = 32; o > 0; o >>= 1) sm += __shfl_down(sm, o);
    if (lane == 0) reds[wv] = sm;

    float part[NQ];
    #pragma unroll
    for (int d = 0; d < NQ; d++) part[d] = 0.0f;
    if (tid < NPATCH) {
        part[0] = w*v0.x; part[1] = w*v0.y; part[2]  = w*v0.z; part[3]  = w*v0.w;
        part[4] = w*v1.x; part[5] = w*v1.y; part[6]  = w*v1.z; part[7]  = w*v1.w;
        part[8] = w*v2.x; part[9] = w*v2.y; part[10] = w*v2.z; part[11] = w*v2.w;
    }
    #pragma unroll
    for (int d = 0; d < NQ; d++) {
        #pragma unroll
        for (int o = 32; o > 0; o >>= 1) part[d] += __shfl_down(part[d], o);
    }
    if (lane == 0) {
        #pragma unroll
        for (int d = 0; d < NQ; d++) redv[wv][d] = part[d];
    }
    __syncthreads();
    if (tid < NQ) {
        float sumv = reds[0] + reds[1] + reds[2] + reds[3];
        float s = redv[0][tid] + redv[1][tid] + redv[2][tid] + redv[3][tid];
        outb[(size_t)b * FEATDIM + qp * NQ + tid] = s / sumv;
    }
}

// ---- Kernel: classifier -----------------------------------------------------
__global__ __launch_bounds__(256) void cls_kernel(
    const float* __restrict__ outb,   // (4,2352)
    const float* __restrict__ Wc,     // (1000,2352)
    const float* __restrict__ bc,     // (1000,)
    float* __restrict__ logits)       // (4,1000)
{
    int o = blockIdx.x, tid = threadIdx.x;
    float acc[NB] = {0.0f, 0.0f, 0.0f, 0.0f};
    const float4* w4 = (const float4*)(Wc + (size_t)o * FEATDIM);
    for (int j = tid; j < FEATDIM / 4; j += 256) {
        float4 w = w4[j];
        #pragma unroll
        for (int b = 0; b < NB; b++) {
            float4 ov = ((const float4*)(outb + (size_t)b * FEATDIM))[j];
            acc[b] += w.x*ov.x + w.y*ov.y + w.z*ov.z + w.w*ov.w;
        }
    }
    #pragma unroll
    for (int b = 0; b < NB; b++) {
        #pragma unroll
        for (int off = 32; off > 0; off >>= 1) acc[b] += __shfl_down(acc[b], off);
    }
    __shared__ float red[4][NB];
    int lane = tid & 63, wv = tid >> 6;
    if (lane == 0) {
        #pragma unroll
        for (int b = 0; b < NB; b++) red[wv][b] = acc[b];
    }
    __syncthreads();
    if (tid < NB) {
        float s = red[0][tid] + red[1][tid] + red[2][tid] + red[3][tid];
        logits[(size_t)tid * NCLS + o] = s + bc[o];
    }
}

// ---- Launch ----------------------------------------------------------------
extern "C" void kernel_launch(void* const* d_in, const int* in_sizes, int n_in,
                              void* d_out, int out_size, void* d_ws, size_t ws_size,
                              hipStream_t stream) {
    const float* x     = (const float*)d_in[0];
    const float* Wp    = (const float*)d_in[1];
    const float* bproj = (const float*)d_in[2];
    const float* qp    = (const float*)d_in[3];
    const float* kp    = (const float*)d_in[4];
    const float* vp    = (const float*)d_in[5];
    const float* Wc    = (const float*)d_in[6];
    const float* bc    = (const float*)d_in[7];
    float* logits = (float*)d_out;

    float* ws   = (float*)d_ws;
    float* qkv  = ws;                 // 3*784*12 = 28224 floats
    float* outb = ws + 28224;         // 4*2352   =  9408 floats

    qcirc_kernel<<<dim3(NPATCH, NB, 3), 128, 0, stream>>>(x, Wp, bproj, qp, kp, vp, qkv);
    attn_kernel <<<dim3(NPATCH, NB),    256, 0, stream>>>(qkv, outb);
    cls_kernel  <<<NCLS,                256, 0, stream>>>(outb, Wc, bc, logits);
}

// Round 10
// 118.826 us; speedup vs baseline: 1.0278x; 1.0278x over previous
//
#include <hip/hip_runtime.h>
#include <math.h>

// ---- Problem constants -----------------------------------------------------
#define NQ        12
#define NPS       14
#define NPATCH    196
#define NB        4
#define NCLS      1000
#define FEATDIM   2352           // 196*12
#define SCALE_F   0.28867513459481287f  // 1/sqrt(12)

typedef float v2f __attribute__((ext_vector_type(2)));

// ---- Layouts (identical to verified round-8 kernel) -------------------------
// 128-thread block (2 waves), 32 amps/thread. Frozen: q2 at amp bit0 (w=1),
// q3 at amp bit1 (w=2) in EVERY layout -> relayout reads are 4-word contiguous
// (b128) AND 16/20 gates per layer act identically on the q2-pair -> packed
// v2f (v_pk_*) math. Storage stride 36 words (144 B, 16B-aligned).
constexpr int PRa[8][5] = {
    {2,3,0,1, 4},   // S1 trio q0,q1,q4
    {2,3,4,5, 6},   // S2 trio q4,q5,q6
    {2,3,5,6, 7},   // S3 trio q5,q6,q7
    {2,3,0,4, 6},   // S4 trio q0,q4,q6
    {2,3,8,9,10},   // S5 trio q8,q9,q10
    {2,3,9,10,11},  // S6 trio q9,q10,q11
    {2,3,0,8,10},   // S7 trio q0,q8,q10
    {2,3,1,5, 9},   // S8 trio q1,q5,q9
};
constexpr int PTa[8][7] = {
    {5,6,7,8,9,10,11},   // S1 | wave q11
    {7,0,1,8,9,10,11},   // S2 | wave q11
    {0,1,4,8,9,10,11},   // S3 | wave q11
    {8,9,10,1,5,7,11},   // S4 | wave q11
    {4,0,1,5,6,7,11},    // S5 | wave q11
    {0,1,8,5,6,7,4},     // S6 | wave q4
    {1,5,9,6,7,11,4},    // S7 | wave q4
    {6,0,11,7,8,10,4},   // S8 | wave q4
};
constexpr bool BARa[8] = {false,false,false,false,true,false,false,true};

constexpr int cwgt(int X, int q) {
    for (int k = 0; k < 5; ++k) if (PRa[X][k] == q) return 1 << k;
    for (int m = 0; m < 7; ++m) if (PTa[X][m] == q) return 36 << m;
    return 0;
}
constexpr int rimmB(int X, int Y, int a) {
    int s = 0;
    for (int j = 0; j < 3; ++j)
        if ((a >> j) & 1) s += cwgt(X, PRa[Y][2 + j]);
    return s;
}

__device__ __forceinline__ void wait_lgkm() {
    __asm__ __volatile__("s_waitcnt lgkmcnt(0)" ::: "memory");
}

template<int TI>
__device__ __forceinline__ void relayoutB(v2f amp2[16], float* lds, int tid, int base) {
    constexpr int X = TI, Y = (TI + 1) & 7;
    float4* dst = (float4*)(lds + 36 * tid);
    #pragma unroll
    for (int k = 0; k < 8; ++k)
        dst[k] = make_float4(amp2[2*k][0], amp2[2*k][1], amp2[2*k+1][0], amp2[2*k+1][1]);
    if (BARa[TI]) __syncthreads(); else wait_lgkm();
    #pragma unroll
    for (int a = 0; a < 8; ++a) {
        float4 v = *(const float4*)(lds + base + rimmB(X, Y, a));
        amp2[2*a][0] = v.x; amp2[2*a][1] = v.y;
        amp2[2*a+1][0] = v.z; amp2[2*a+1][1] = v.w;
    }
    if (BARa[TI]) __syncthreads();
}

// Packed RBS gate: masks MI,MJ in amp2-index space (amp mask >> 1).
// Half-angle form: gc = 0.5*cos(2t), gs = 0.5*sin(2t). Same role order as r8.
template<int MI, int MJ>
__device__ __forceinline__ void pk_gate(v2f a[16], float gc, float gs) {
    v2f H = {0.5f, 0.5f}, C = {gc, gc}, S = {gs, gs};
    #pragma unroll
    for (int m = 0; m < 16; ++m) {
        if (m & (MI | MJ)) continue;
        v2f a0 = a[m], a1 = a[m | MJ], a2 = a[m | MI], a3 = a[m | MI | MJ];
        v2f p  = a0 + a1, q  = a0 - a1;
        v2f p2 = a2 + a3, q2 = a2 - a3;
        v2f t1 = H * p  + C * q  - S * q2;
        v2f t2 = H * p2 + C * q2 + S * q;
        a[m]           = t1;
        a[m | MJ]      = p  - t1;
        a[m | MI]      = t2;
        a[m | MI | MJ] = p2 - t2;
    }
}

// Scalar RBS gate (for gates touching q2 = amp bit0), float view of amp2.
template<int MI, int MJ>
__device__ __forceinline__ void sc_gate(float* amp, float gc, float gs) {
    #pragma unroll
    for (int m = 0; m < 32; ++m) {
        if (m & (MI | MJ)) continue;
        float a0 = amp[m], a1 = amp[m | MJ], a2 = amp[m | MI], a3 = amp[m | MI | MJ];
        float p  = a0 + a1, q  = a0 - a1;
        float p2 = a2 + a3, q2 = a2 - a3;
        float t1 = 0.5f * p  + gc * q  - gs * q2;
        float t2 = 0.5f * p2 + gc * q2 + gs * q;
        amp[m]           = t1;
        amp[m | MJ]      = p  - t1;
        amp[m | MI]      = t2;
        amp[m | MI | MJ] = p2 - t2;
    }
}

// ---- DPP wave-wide sum (result valid in lane 63), pure VALU ----------------
template<int CTRL>
__device__ __forceinline__ float dppadd(float x) {
    int s = __builtin_amdgcn_update_dpp(0, __float_as_int(x), CTRL, 0xf, 0xf, true);
    return x + __int_as_float(s);
}
__device__ __forceinline__ float wave_sum(float x) {
    x = dppadd<0x111>(x);   // row_shr:1
    x = dppadd<0x112>(x);   // row_shr:2
    x = dppadd<0x114>(x);   // row_shr:4
    x = dppadd<0x118>(x);   // row_shr:8
    x = dppadd<0x142>(x);   // row_bcast:15
    x = dppadd<0x143>(x);   // row_bcast:31
    return x;
}

// ---- Kernel: fused projection + quantum circuit ----------------------------
// grid (196, 4, 3), block 128 (two waves). LDS ~18.9 KB.
__global__ __launch_bounds__(128, 4) void qcirc_kernel(
    const float* __restrict__ x,      // (4,3,224,224)
    const float* __restrict__ Wp,     // (12,256)
    const float* __restrict__ bproj,  // (12,)
    const float* __restrict__ qp,
    const float* __restrict__ kp,
    const float* __restrict__ vp,
    float* __restrict__ qkv)          // (3,784,12)
{
    __shared__ __align__(16) float lds[4608];   // 36*128 words
    __shared__ float chs[NQ], shs[NQ];
    __shared__ float gC[40], gS[40];
    __shared__ float red2[2][12];

    const int tid = threadIdx.x;
    const int p = blockIdx.x, b = blockIdx.y, c = blockIdx.z;
    const int bp = b * NPATCH + p;
    const float* params = (c == 0) ? qp : (c == 1) ? kp : vp;
    const int lane = tid & 63, wv = tid >> 6;

    // ---- projection: 2 pixels/thread, DPP wave sums ----
    float part[NQ];
    #pragma unroll
    for (int q = 0; q < NQ; ++q) part[q] = 0.0f;
    {
        int py = p / NPS, px = p % NPS;
        const float* xb = x + (size_t)b * 3 * 224 * 224;
        #pragma unroll
        for (int k = 0; k < 2; ++k) {
            int pix = tid + 128 * k;
            int off = (py * 16 + (pix >> 4)) * 224 + px * 16 + (pix & 15);
            float v = (xb[off] + xb[off + 50176] + xb[off + 100352]) * (1.0f / 3.0f);
            #pragma unroll
            for (int q = 0; q < NQ; ++q) part[q] += v * Wp[q * 256 + pix];
        }
    }
    if (tid < 40) {
        int l = tid / 20, g = tid - l * 20;
        float th = params[l * 32 + g];
        gC[tid] = 0.5f * cosf(2.0f * th);
        gS[tid] = 0.5f * sinf(2.0f * th);
    }
    #pragma unroll
    for (int q = 0; q < NQ; ++q) part[q] = wave_sum(part[q]);
    if (lane == 63) {
        #pragma unroll
        for (int q = 0; q < NQ; ++q) red2[wv][q] = part[q];
    }
    __syncthreads();
    if (tid < NQ) {
        float h = 0.5f * (red2[0][tid] + red2[1][tid] + bproj[tid]);
        chs[tid] = cosf(h); shs[tid] = sinf(h);
    }
    __syncthreads();

    // ---- precompute relayout read bases (8 transitions, reused both layers) ----
    int baseT[8];
    #pragma unroll
    for (int TI = 0; TI < 8; ++TI) {
        int Y = (TI + 1) & 7, s = 0;
        #pragma unroll
        for (int j = 0; j < 7; ++j)
            s += ((tid >> j) & 1) ? cwgt(TI, PTa[Y][j]) : 0;
        baseT[TI] = s;
    }

    // ---- init in S1: amp b0=q2 b1=q3 b2=q0 b3=q1 b4=q4;
    //      tid t0=q5 t1=q6 t2=q7 t3=q8 t4=q9 t5=q10 | wave t6=q11 ----
    v2f amp2[16];
    float* amp = (float*)amp2;
    {
        float hi = ((tid &  1) ? shs[5]  : chs[5])  *
                   ((tid &  2) ? shs[6]  : chs[6])  *
                   ((tid &  4) ? shs[7]  : chs[7])  *
                   ((tid &  8) ? shs[8]  : chs[8])  *
                   ((tid & 16) ? shs[9]  : chs[9])  *
                   ((tid & 32) ? shs[10] : chs[10]) *
                   ((tid & 64) ? shs[11] : chs[11]);
        float pA[8], pB[4];
        #pragma unroll
        for (int i = 0; i < 8; ++i)
            pA[i] = ((i & 1) ? shs[2] : chs[2]) * ((i & 2) ? shs[3] : chs[3]) *
                    ((i & 4) ? shs[0] : chs[0]);
        #pragma unroll
        for (int i = 0; i < 4; ++i)
            pB[i] = ((i & 1) ? shs[1] : chs[1]) * ((i & 2) ? shs[4] : chs[4]);
        #pragma unroll
        for (int r = 0; r < 32; ++r) amp[r] = pA[r & 7] * pB[r >> 3] * hi;
    }

    // ---- 2 layers x 8 runs; 15 relayouts; schedule identical to verified r8.
    //      Packed masks = r8 amp masks >> 1; gates touching q2 (mask bit0)
    //      stay scalar: p1,p6,p14,p18. ----
    #pragma unroll 1
    for (int l = 0; l < 2; ++l) {
        const int bb = l * 20;
        // S1 trio(q0,q1,q4): p0(0,1) p1(2,3) p6(0,2) p7(1,3)
        pk_gate<2, 4>(amp2, gC[bb+0], gS[bb+0]);   // was <4,8>
        sc_gate<1, 2>(amp,  gC[bb+1], gS[bb+1]);
        sc_gate<4, 1>(amp,  gC[bb+6], gS[bb+6]);
        pk_gate<4, 1>(amp2, gC[bb+7], gS[bb+7]);   // was <8,2>
        relayoutB<0>(amp2, lds, tid, baseT[0]);
        // S2 trio(q4,q5,q6): p2(4,5)
        pk_gate<2, 4>(amp2, gC[bb+2], gS[bb+2]);   // was <4,8>
        relayoutB<1>(amp2, lds, tid, baseT[1]);
        // S3 trio(q5,q6,q7): p3(6,7) p9(5,7) p15(3,7)
        pk_gate<4, 8>(amp2, gC[bb+3],  gS[bb+3]);  // was <8,16>
        pk_gate<2, 8>(amp2, gC[bb+9],  gS[bb+9]);  // was <4,16>
        pk_gate<1, 8>(amp2, gC[bb+15], gS[bb+15]); // was <2,16>
        relayoutB<2>(amp2, lds, tid, baseT[2]);
        // S4 trio(q0,q4,q6): p8(4,6) p12(0,4) p14(2,6)
        pk_gate<4, 8>(amp2, gC[bb+8],  gS[bb+8]);  // was <8,16>
        pk_gate<2, 4>(amp2, gC[bb+12], gS[bb+12]); // was <4,8>
        sc_gate<1,16>(amp,  gC[bb+14], gS[bb+14]);
        relayoutB<3>(amp2, lds, tid, baseT[3]);
        // S5 trio(q8,q9,q10): p4(8,9)
        pk_gate<2, 4>(amp2, gC[bb+4], gS[bb+4]);   // was <4,8>
        relayoutB<4>(amp2, lds, tid, baseT[4]);
        // S6 trio(q9,q10,q11): p5(10,11) p11(9,11) p19(3,11)
        pk_gate<4, 8>(amp2, gC[bb+5],  gS[bb+5]);  // was <8,16>
        pk_gate<2, 8>(amp2, gC[bb+11], gS[bb+11]); // was <4,16>
        pk_gate<1, 8>(amp2, gC[bb+19], gS[bb+19]); // was <2,16>
        relayoutB<5>(amp2, lds, tid, baseT[5]);
        // S7 trio(q0,q8,q10): p10(8,10) p16(0,8) p18(2,10)
        pk_gate<4, 8>(amp2, gC[bb+10], gS[bb+10]); // was <8,16>
        pk_gate<2, 4>(amp2, gC[bb+16], gS[bb+16]); // was <4,8>
        sc_gate<1,16>(amp,  gC[bb+18], gS[bb+18]);
        relayoutB<6>(amp2, lds, tid, baseT[6]);
        // S8 trio(q1,q5,q9): p13(1,5) p17(1,9)
        pk_gate<2, 4>(amp2, gC[bb+13], gS[bb+13]); // was <4,8>
        pk_gate<2, 8>(amp2, gC[bb+17], gS[bb+17]); // was <4,16>
        if (l == 0) relayoutB<7>(amp2, lds, tid, baseT[7]);
    }

    // ---- expvals in S8: amp b0=q2 b1=q3 b2=q1 b3=q5 b4=q9;
    //      tid t0=q6 t1=q0 t2=q11 t3=q7 t4=q8 t5=q10 | wave t6=q4 ----
    float T, Sq2, Sq3, Sq1, Sq5, Sq9;
    {
        float t1[16]; Sq2 = 0.0f;
        #pragma unroll
        for (int i = 0; i < 16; ++i) {
            float e = amp[2*i] * amp[2*i], o = amp[2*i+1] * amp[2*i+1];
            t1[i] = e + o; Sq2 += e - o;
        }
        float t2[8]; Sq3 = 0.0f;
        #pragma unroll
        for (int i = 0; i < 8; ++i) { t2[i] = t1[2*i] + t1[2*i+1]; Sq3 += t1[2*i] - t1[2*i+1]; }
        float t3[4]; Sq1 = 0.0f;
        #pragma unroll
        for (int i = 0; i < 4; ++i) { t3[i] = t2[2*i] + t2[2*i+1]; Sq1 += t2[2*i] - t2[2*i+1]; }
        float t4[2]; Sq5 = 0.0f;
        #pragma unroll
        for (int i = 0; i < 2; ++i) { t4[i] = t3[2*i] + t3[2*i+1]; Sq5 += t3[2*i] - t3[2*i+1]; }
        T = t4[0] + t4[1]; Sq9 = t4[0] - t4[1];
    }
    float Vq6  = (tid &  1) ? -T : T;
    float Vq0  = (tid &  2) ? -T : T;
    float Vq11 = (tid &  4) ? -T : T;
    float Vq7  = (tid &  8) ? -T : T;
    float Vq8  = (tid & 16) ? -T : T;
    float Vq10 = (tid & 32) ? -T : T;
    T    = wave_sum(T);
    Vq6  = wave_sum(Vq6);  Vq0  = wave_sum(Vq0);  Vq11 = wave_sum(Vq11);
    Vq7  = wave_sum(Vq7);  Vq8  = wave_sum(Vq8);  Vq10 = wave_sum(Vq10);
    Sq2  = wave_sum(Sq2);  Sq3  = wave_sum(Sq3);  Sq1  = wave_sum(Sq1);
    Sq5  = wave_sum(Sq5);  Sq9  = wave_sum(Sq9);
    if (lane == 63) {
        red2[wv][0]  = Vq0;  red2[wv][1]  = Sq1;  red2[wv][2]  = Sq2;
        red2[wv][3]  = Sq3;  red2[wv][4]  = T;    red2[wv][5]  = Sq5;
        red2[wv][6]  = Vq6;  red2[wv][7]  = Vq7;  red2[wv][8]  = Vq8;
        red2[wv][9]  = Sq9;  red2[wv][10] = Vq10; red2[wv][11] = Vq11;
    }
    __syncthreads();
    if (tid < NQ) {
        float v1 = red2[1][tid];
        float s = red2[0][tid] + ((tid == 4) ? -v1 : v1);   // wave bit = q4
        qkv[((size_t)c * (NB * NPATCH) + bp) * NQ + tid] = s;
    }
}

// ---- Kernel: attention ------------------------------------------------------
__global__ __launch_bounds__(256) void attn_kernel(
    const float* __restrict__ qkv,    // (3,784,12)
    float* __restrict__ outb)         // (4,2352)
{
    int tid = threadIdx.x;
    int qp = blockIdx.x, b = blockIdx.y;
    const float* Q = qkv;
    const float* K = qkv + NB * NPATCH * NQ;
    const float* V = qkv + 2 * NB * NPATCH * NQ;

    __shared__ float redm[4], reds[4], redv[4][NQ];

    float4 q0 = ((const float4*)(Q + (b * NPATCH + qp) * NQ))[0];
    float4 q1 = ((const float4*)(Q + (b * NPATCH + qp) * NQ))[1];
    float4 q2 = ((const float4*)(Q + (b * NPATCH + qp) * NQ))[2];

    float score = -1e30f;
    float4 v0, v1, v2;
    if (tid < NPATCH) {
        const float4* K4 = (const float4*)(K + (b * NPATCH + tid) * NQ);
        float4 k0 = K4[0], k1 = K4[1], k2 = K4[2];
        float s = q0.x*k0.x + q0.y*k0.y + q0.z*k0.z + q0.w*k0.w
                + q1.x*k1.x + q1.y*k1.y + q1.z*k1.z + q1.w*k1.w
                + q2.x*k2.x + q2.y*k2.y + q2.z*k2.z + q2.w*k2.w;
        score = s * SCALE_F;
        const float4* V4 = (const float4*)(V + (b * NPATCH + tid) * NQ);
        v0 = V4[0]; v1 = V4[1]; v2 = V4[2];
    }
    float m = score;
    #pragma unroll
    for (int o = 32; o > 0; o >>= 1) m = fmaxf(m, __shfl_down(m, o));
    int lane = tid & 63, wv = tid >> 6;
    if (lane == 0) redm[wv] = m;
    __syncthreads();
    float maxv = fmaxf(fmaxf(redm[0], redm[1]), fmaxf(redm[2], redm[3]));

    float w = (tid < NPATCH) ? expf(score - maxv) : 0.0f;
    float sm = w;
    #pragma unroll
    for (int o = 32; o > 0; o >>= 1) sm += __shfl_down(sm, o);
    if (lane == 0) reds[wv] = sm;

    float part[NQ];
    #pragma unroll
    for (int d = 0; d < NQ; d++) part[d] = 0.0f;
    if (tid < NPATCH) {
        part[0] = w*v0.x; part[1] = w*v0.y; part[2]  = w*v0.z; part[3]  = w*v0.w;
        part[4] = w*v1.x; part[5] = w*v1.y; part[6]  = w*v1.z; part[7]  = w*v1.w;
        part[8] = w*v2.x; part[9] = w*v2.y; part[10] = w*v2.z; part[11] = w*v2.w;
    }
    #pragma unroll
    for (int d = 0; d < NQ; d++) {
        #pragma unroll
        for (int o = 32; o > 0; o >>= 1) part[d] += __shfl_down(part[d], o);
    }
    if (lane == 0) {
        #pragma unroll
        for (int d = 0; d < NQ; d++) redv[wv][d] = part[d];
    }
    __syncthreads();
    if (tid < NQ) {
        float sumv = reds[0] + reds[1] + reds[2] + reds[3];
        float s = redv[0][tid] + redv[1][tid] + redv[2][tid] + redv[3][tid];
        outb[(size_t)b * FEATDIM + qp * NQ + tid] = s / sumv;
    }
}

// ---- Kernel: classifier -----------------------------------------------------
__global__ __launch_bounds__(256) void cls_kernel(
    const float* __restrict__ outb,   // (4,2352)
    const float* __restrict__ Wc,     // (1000,2352)
    const float* __restrict__ bc,     // (1000,)
    float* __restrict__ logits)       // (4,1000)
{
    int o = blockIdx.x, tid = threadIdx.x;
    float acc[NB] = {0.0f, 0.0f, 0.0f, 0.0f};
    const float4* w4 = (const float4*)(Wc + (size_t)o * FEATDIM);
    for (int j = tid; j < FEATDIM / 4; j += 256) {
        float4 w = w4[j];
        #pragma unroll
        for (int b = 0; b < NB; b++) {
            float4 ov = ((const float4*)(outb + (size_t)b * FEATDIM))[j];
            acc[b] += w.x*ov.x + w.y*ov.y + w.z*ov.z + w.w*ov.w;
        }
    }
    #pragma unroll
    for (int b = 0; b < NB; b++) {
        #pragma unroll
        for (int off = 32; off > 0; off >>= 1) acc[b] += __shfl_down(acc[b], off);
    }
    __shared__ float red[4][NB];
    int lane = tid & 63, wv = tid >> 6;
    if (lane == 0) {
        #pragma unroll
        for (int b = 0; b < NB; b++) red[wv][b] = acc[b];
    }
    __syncthreads();
    if (tid < NB) {
        float s = red[0][tid] + red[1][tid] + red[2][tid] + red[3][tid];
        logits[(size_t)tid * NCLS + o] = s + bc[o];
    }
}

// ---- Launch ----------------------------------------------------------------
extern "C" void kernel_launch(void* const* d_in, const int* in_sizes, int n_in,
                              void* d_out, int out_size, void* d_ws, size_t ws_size,
                              hipStream_t stream) {
    const float* x     = (const float*)d_in[0];
    const float* Wp    = (const float*)d_in[1];
    const float* bproj = (const float*)d_in[2];
    const float* qp    = (const float*)d_in[3];
    const float* kp    = (const float*)d_in[4];
    const float* vp    = (const float*)d_in[5];
    const float* Wc    = (const float*)d_in[6];
    const float* bc    = (const float*)d_in[7];
    float* logits = (float*)d_out;

    float* ws   = (float*)d_ws;
    float* qkv  = ws;                 // 3*784*12 = 28224 floats
    float* outb = ws + 28224;         // 4*2352   =  9408 floats

    qcirc_kernel<<<dim3(NPATCH, NB, 3), 128, 0, stream>>>(x, Wp, bproj, qp, kp, vp, qkv);
    attn_kernel <<<dim3(NPATCH, NB),    256, 0, stream>>>(qkv, outb);
    cls_kernel  <<<NCLS,                256, 0, stream>>>(outb, Wc, bc, logits);
}

// Round 11
// 116.031 us; speedup vs baseline: 1.0525x; 1.0241x over previous
//
#include <hip/hip_runtime.h>
#include <math.h>

// ---- Problem constants -----------------------------------------------------
#define NQ        12
#define NPS       14
#define NPATCH    196
#define NB        4
#define NCLS      1000
#define FEATDIM   2352           // 196*12
#define SCALE_F   0.28867513459481287f  // 1/sqrt(12)

typedef float v2f __attribute__((ext_vector_type(2)));

// ---- Layouts (identical to verified round-8/9 kernels) ----------------------
// 128-thread block (2 waves), 32 amps/thread. Frozen: q2 at amp bit0 (w=1),
// q3 at amp bit1 (w=2) in EVERY layout -> relayout reads are 4-word contiguous
// (b128) AND 16/20 gates per layer act identically on the q2-pair -> packed
// v2f (v_pk_*) math. Storage stride 36 words (144 B, 16B-aligned).
constexpr int PRa[8][5] = {
    {2,3,0,1, 4},   // S1 trio q0,q1,q4
    {2,3,4,5, 6},   // S2 trio q4,q5,q6
    {2,3,5,6, 7},   // S3 trio q5,q6,q7
    {2,3,0,4, 6},   // S4 trio q0,q4,q6
    {2,3,8,9,10},   // S5 trio q8,q9,q10
    {2,3,9,10,11},  // S6 trio q9,q10,q11
    {2,3,0,8,10},   // S7 trio q0,q8,q10
    {2,3,1,5, 9},   // S8 trio q1,q5,q9
};
constexpr int PTa[8][7] = {
    {5,6,7,8,9,10,11},   // S1 | wave q11
    {7,0,1,8,9,10,11},   // S2 | wave q11
    {0,1,4,8,9,10,11},   // S3 | wave q11
    {8,9,10,1,5,7,11},   // S4 | wave q11
    {4,0,1,5,6,7,11},    // S5 | wave q11
    {0,1,8,5,6,7,4},     // S6 | wave q4
    {1,5,9,6,7,11,4},    // S7 | wave q4
    {6,0,11,7,8,10,4},   // S8 | wave q4
};
constexpr bool BARa[8] = {false,false,false,false,true,false,false,true};

constexpr int cwgt(int X, int q) {
    for (int k = 0; k < 5; ++k) if (PRa[X][k] == q) return 1 << k;
    for (int m = 0; m < 7; ++m) if (PTa[X][m] == q) return 36 << m;
    return 0;
}
constexpr int rimmB(int X, int Y, int a) {
    int s = 0;
    for (int j = 0; j < 3; ++j)
        if ((a >> j) & 1) s += cwgt(X, PRa[Y][2 + j]);
    return s;
}

// Intra-wave relayouts (BAR=false) need NO explicit sync: LDS processes a
// wave's DS instructions in program order, so the wave-wide ds_read after the
// wave-wide ds_write sees all lanes' data; the compiler inserts fine-grained
// lgkmcnt(N) only before each chunk's first VALU use -> reads and gate math
// on early chunks overlap the tail of the LDS traffic. Cross-wave transitions
// (wave qubit changes, BAR=true) keep full __syncthreads.
template<int TI>
__device__ __forceinline__ void relayoutB(v2f amp2[16], float* lds, int tid, int base) {
    constexpr int X = TI, Y = (TI + 1) & 7;
    float4* dst = (float4*)(lds + 36 * tid);
    #pragma unroll
    for (int k = 0; k < 8; ++k)
        dst[k] = make_float4(amp2[2*k][0], amp2[2*k][1], amp2[2*k+1][0], amp2[2*k+1][1]);
    if (BARa[TI]) __syncthreads();
    #pragma unroll
    for (int a = 0; a < 8; ++a) {
        float4 v = *(const float4*)(lds + base + rimmB(X, Y, a));
        amp2[2*a][0] = v.x; amp2[2*a][1] = v.y;
        amp2[2*a+1][0] = v.z; amp2[2*a+1][1] = v.w;
    }
    if (BARa[TI]) __syncthreads();
}

// Packed RBS gate: masks MI,MJ in amp2-index space (amp mask >> 1).
// Half-angle form: gc = 0.5*cos(2t), gs = 0.5*sin(2t).
template<int MI, int MJ>
__device__ __forceinline__ void pk_gate(v2f a[16], float gc, float gs) {
    v2f H = {0.5f, 0.5f}, C = {gc, gc}, S = {gs, gs};
    #pragma unroll
    for (int m = 0; m < 16; ++m) {
        if (m & (MI | MJ)) continue;
        v2f a0 = a[m], a1 = a[m | MJ], a2 = a[m | MI], a3 = a[m | MI | MJ];
        v2f p  = a0 + a1, q  = a0 - a1;
        v2f p2 = a2 + a3, q2 = a2 - a3;
        v2f t1 = H * p  + C * q  - S * q2;
        v2f t2 = H * p2 + C * q2 + S * q;
        a[m]           = t1;
        a[m | MJ]      = p  - t1;
        a[m | MI]      = t2;
        a[m | MI | MJ] = p2 - t2;
    }
}

// Scalar RBS gate (for gates touching q2 = amp bit0), float view of amp2.
template<int MI, int MJ>
__device__ __forceinline__ void sc_gate(float* amp, float gc, float gs) {
    #pragma unroll
    for (int m = 0; m < 32; ++m) {
        if (m & (MI | MJ)) continue;
        float a0 = amp[m], a1 = amp[m | MJ], a2 = amp[m | MI], a3 = amp[m | MI | MJ];
        float p  = a0 + a1, q  = a0 - a1;
        float p2 = a2 + a3, q2 = a2 - a3;
        float t1 = 0.5f * p  + gc * q  - gs * q2;
        float t2 = 0.5f * p2 + gc * q2 + gs * q;
        amp[m]           = t1;
        amp[m | MJ]      = p  - t1;
        amp[m | MI]      = t2;
        amp[m | MI | MJ] = p2 - t2;
    }
}

// ---- DPP wave-wide sum (result valid in lane 63), pure VALU ----------------
template<int CTRL>
__device__ __forceinline__ float dppadd(float x) {
    int s = __builtin_amdgcn_update_dpp(0, __float_as_int(x), CTRL, 0xf, 0xf, true);
    return x + __int_as_float(s);
}
__device__ __forceinline__ float wave_sum(float x) {
    x = dppadd<0x111>(x);   // row_shr:1
    x = dppadd<0x112>(x);   // row_shr:2
    x = dppadd<0x114>(x);   // row_shr:4
    x = dppadd<0x118>(x);   // row_shr:8
    x = dppadd<0x142>(x);   // row_bcast:15
    x = dppadd<0x143>(x);   // row_bcast:31
    return x;
}

// ---- Kernel: fused projection + quantum circuit ----------------------------
// grid (196, 4, 3), block 128 (two waves). LDS ~18.9 KB.
__global__ __launch_bounds__(128, 4) void qcirc_kernel(
    const float* __restrict__ x,      // (4,3,224,224)
    const float* __restrict__ Wp,     // (12,256)
    const float* __restrict__ bproj,  // (12,)
    const float* __restrict__ qp,
    const float* __restrict__ kp,
    const float* __restrict__ vp,
    float* __restrict__ qkv)          // (3,784,12)
{
    __shared__ __align__(16) float lds[4608];   // 36*128 words
    __shared__ float chs[NQ], shs[NQ];
    __shared__ float gC[40], gS[40];
    __shared__ float red2[2][12];

    const int tid = threadIdx.x;
    const int p = blockIdx.x, b = blockIdx.y, c = blockIdx.z;
    const int bp = b * NPATCH + p;
    const float* params = (c == 0) ? qp : (c == 1) ? kp : vp;
    const int lane = tid & 63, wv = tid >> 6;

    // ---- projection: 2 pixels/thread, DPP wave sums ----
    float part[NQ];
    #pragma unroll
    for (int q = 0; q < NQ; ++q) part[q] = 0.0f;
    {
        int py = p / NPS, px = p % NPS;
        const float* xb = x + (size_t)b * 3 * 224 * 224;
        #pragma unroll
        for (int k = 0; k < 2; ++k) {
            int pix = tid + 128 * k;
            int off = (py * 16 + (pix >> 4)) * 224 + px * 16 + (pix & 15);
            float v = (xb[off] + xb[off + 50176] + xb[off + 100352]) * (1.0f / 3.0f);
            #pragma unroll
            for (int q = 0; q < NQ; ++q) part[q] += v * Wp[q * 256 + pix];
        }
    }
    if (tid < 40) {
        int l = tid / 20, g = tid - l * 20;
        float th = params[l * 32 + g];
        gC[tid] = 0.5f * cosf(2.0f * th);
        gS[tid] = 0.5f * sinf(2.0f * th);
    }
    #pragma unroll
    for (int q = 0; q < NQ; ++q) part[q] = wave_sum(part[q]);
    if (lane == 63) {
        #pragma unroll
        for (int q = 0; q < NQ; ++q) red2[wv][q] = part[q];
    }
    __syncthreads();
    if (tid < NQ) {
        float h = 0.5f * (red2[0][tid] + red2[1][tid] + bproj[tid]);
        chs[tid] = cosf(h); shs[tid] = sinf(h);
    }
    __syncthreads();

    // ---- precompute relayout read bases (8 transitions, reused both layers) ----
    int baseT[8];
    #pragma unroll
    for (int TI = 0; TI < 8; ++TI) {
        int Y = (TI + 1) & 7, s = 0;
        #pragma unroll
        for (int j = 0; j < 7; ++j)
            s += ((tid >> j) & 1) ? cwgt(TI, PTa[Y][j]) : 0;
        baseT[TI] = s;
    }

    // ---- init in S1: amp b0=q2 b1=q3 b2=q0 b3=q1 b4=q4;
    //      tid t0=q5 t1=q6 t2=q7 t3=q8 t4=q9 t5=q10 | wave t6=q11 ----
    v2f amp2[16];
    float* amp = (float*)amp2;
    {
        float hi = ((tid &  1) ? shs[5]  : chs[5])  *
                   ((tid &  2) ? shs[6]  : chs[6])  *
                   ((tid &  4) ? shs[7]  : chs[7])  *
                   ((tid &  8) ? shs[8]  : chs[8])  *
                   ((tid & 16) ? shs[9]  : chs[9])  *
                   ((tid & 32) ? shs[10] : chs[10]) *
                   ((tid & 64) ? shs[11] : chs[11]);
        float pA[8], pB[4];
        #pragma unroll
        for (int i = 0; i < 8; ++i)
            pA[i] = ((i & 1) ? shs[2] : chs[2]) * ((i & 2) ? shs[3] : chs[3]) *
                    ((i & 4) ? shs[0] : chs[0]);
        #pragma unroll
        for (int i = 0; i < 4; ++i)
            pB[i] = ((i & 1) ? shs[1] : chs[1]) * ((i & 2) ? shs[4] : chs[4]);
        #pragma unroll
        for (int r = 0; r < 32; ++r) amp[r] = pA[r & 7] * pB[r >> 3] * hi;
    }

    // ---- 2 layers x 8 runs; 15 relayouts; schedule identical to verified r8/r9.
    //      Packed masks = r8 amp masks >> 1; gates touching q2 (mask bit0)
    //      stay scalar: p1,p6,p14,p18. ----
    #pragma unroll 1
    for (int l = 0; l < 2; ++l) {
        const int bb = l * 20;
        // S1 trio(q0,q1,q4): p0(0,1) p1(2,3) p6(0,2) p7(1,3)
        pk_gate<2, 4>(amp2, gC[bb+0], gS[bb+0]);
        sc_gate<1, 2>(amp,  gC[bb+1], gS[bb+1]);
        sc_gate<4, 1>(amp,  gC[bb+6], gS[bb+6]);
        pk_gate<4, 1>(amp2, gC[bb+7], gS[bb+7]);
        relayoutB<0>(amp2, lds, tid, baseT[0]);
        // S2 trio(q4,q5,q6): p2(4,5)
        pk_gate<2, 4>(amp2, gC[bb+2], gS[bb+2]);
        relayoutB<1>(amp2, lds, tid, baseT[1]);
        // S3 trio(q5,q6,q7): p3(6,7) p9(5,7) p15(3,7)
        pk_gate<4, 8>(amp2, gC[bb+3],  gS[bb+3]);
        pk_gate<2, 8>(amp2, gC[bb+9],  gS[bb+9]);
        pk_gate<1, 8>(amp2, gC[bb+15], gS[bb+15]);
        relayoutB<2>(amp2, lds, tid, baseT[2]);
        // S4 trio(q0,q4,q6): p8(4,6) p12(0,4) p14(2,6)
        pk_gate<4, 8>(amp2, gC[bb+8],  gS[bb+8]);
        pk_gate<2, 4>(amp2, gC[bb+12], gS[bb+12]);
        sc_gate<1,16>(amp,  gC[bb+14], gS[bb+14]);
        relayoutB<3>(amp2, lds, tid, baseT[3]);
        // S5 trio(q8,q9,q10): p4(8,9)
        pk_gate<2, 4>(amp2, gC[bb+4], gS[bb+4]);
        relayoutB<4>(amp2, lds, tid, baseT[4]);
        // S6 trio(q9,q10,q11): p5(10,11) p11(9,11) p19(3,11)
        pk_gate<4, 8>(amp2, gC[bb+5],  gS[bb+5]);
        pk_gate<2, 8>(amp2, gC[bb+11], gS[bb+11]);
        pk_gate<1, 8>(amp2, gC[bb+19], gS[bb+19]);
        relayoutB<5>(amp2, lds, tid, baseT[5]);
        // S7 trio(q0,q8,q10): p10(8,10) p16(0,8) p18(2,10)
        pk_gate<4, 8>(amp2, gC[bb+10], gS[bb+10]);
        pk_gate<2, 4>(amp2, gC[bb+16], gS[bb+16]);
        sc_gate<1,16>(amp,  gC[bb+18], gS[bb+18]);
        relayoutB<6>(amp2, lds, tid, baseT[6]);
        // S8 trio(q1,q5,q9): p13(1,5) p17(1,9)
        pk_gate<2, 4>(amp2, gC[bb+13], gS[bb+13]);
        pk_gate<2, 8>(amp2, gC[bb+17], gS[bb+17]);
        if (l == 0) relayoutB<7>(amp2, lds, tid, baseT[7]);
    }

    // ---- expvals in S8: amp b0=q2 b1=q3 b2=q1 b3=q5 b4=q9;
    //      tid t0=q6 t1=q0 t2=q11 t3=q7 t4=q8 t5=q10 | wave t6=q4 ----
    float T, Sq2, Sq3, Sq1, Sq5, Sq9;
    {
        float t1[16]; Sq2 = 0.0f;
        #pragma unroll
        for (int i = 0; i < 16; ++i) {
            float e = amp[2*i] * amp[2*i], o = amp[2*i+1] * amp[2*i+1];
            t1[i] = e + o; Sq2 += e - o;
        }
        float t2[8]; Sq3 = 0.0f;
        #pragma unroll
        for (int i = 0; i < 8; ++i) { t2[i] = t1[2*i] + t1[2*i+1]; Sq3 += t1[2*i] - t1[2*i+1]; }
        float t3[4]; Sq1 = 0.0f;
        #pragma unroll
        for (int i = 0; i < 4; ++i) { t3[i] = t2[2*i] + t2[2*i+1]; Sq1 += t2[2*i] - t2[2*i+1]; }
        float t4[2]; Sq5 = 0.0f;
        #pragma unroll
        for (int i = 0; i < 2; ++i) { t4[i] = t3[2*i] + t3[2*i+1]; Sq5 += t3[2*i] - t3[2*i+1]; }
        T = t4[0] + t4[1]; Sq9 = t4[0] - t4[1];
    }
    float Vq6  = (tid &  1) ? -T : T;
    float Vq0  = (tid &  2) ? -T : T;
    float Vq11 = (tid &  4) ? -T : T;
    float Vq7  = (tid &  8) ? -T : T;
    float Vq8  = (tid & 16) ? -T : T;
    float Vq10 = (tid & 32) ? -T : T;
    T    = wave_sum(T);
    Vq6  = wave_sum(Vq6);  Vq0  = wave_sum(Vq0);  Vq11 = wave_sum(Vq11);
    Vq7  = wave_sum(Vq7);  Vq8  = wave_sum(Vq8);  Vq10 = wave_sum(Vq10);
    Sq2  = wave_sum(Sq2);  Sq3  = wave_sum(Sq3);  Sq1  = wave_sum(Sq1);
    Sq5  = wave_sum(Sq5);  Sq9  = wave_sum(Sq9);
    if (lane == 63) {
        red2[wv][0]  = Vq0;  red2[wv][1]  = Sq1;  red2[wv][2]  = Sq2;
        red2[wv][3]  = Sq3;  red2[wv][4]  = T;    red2[wv][5]  = Sq5;
        red2[wv][6]  = Vq6;  red2[wv][7]  = Vq7;  red2[wv][8]  = Vq8;
        red2[wv][9]  = Sq9;  red2[wv][10] = Vq10; red2[wv][11] = Vq11;
    }
    __syncthreads();
    if (tid < NQ) {
        float v1 = red2[1][tid];
        float s = red2[0][tid] + ((tid == 4) ? -v1 : v1);   // wave bit = q4
        qkv[((size_t)c * (NB * NPATCH) + bp) * NQ + tid] = s;
    }
}

// ---- Kernel: attention ------------------------------------------------------
__global__ __launch_bounds__(256) void attn_kernel(
    const float* __restrict__ qkv,    // (3,784,12)
    float* __restrict__ outb)         // (4,2352)
{
    int tid = threadIdx.x;
    int qp = blockIdx.x, b = blockIdx.y;
    const float* Q = qkv;
    const float* K = qkv + NB * NPATCH * NQ;
    const float* V = qkv + 2 * NB * NPATCH * NQ;

    __shared__ float redm[4], reds[4], redv[4][NQ];

    float4 q0 = ((const float4*)(Q + (b * NPATCH + qp) * NQ))[0];
    float4 q1 = ((const float4*)(Q + (b * NPATCH + qp) * NQ))[1];
    float4 q2 = ((const float4*)(Q + (b * NPATCH + qp) * NQ))[2];

    float score = -1e30f;
    float4 v0, v1, v2;
    if (tid < NPATCH) {
        const float4* K4 = (const float4*)(K + (b * NPATCH + tid) * NQ);
        float4 k0 = K4[0], k1 = K4[1], k2 = K4[2];
        float s = q0.x*k0.x + q0.y*k0.y + q0.z*k0.z + q0.w*k0.w
                + q1.x*k1.x + q1.y*k1.y + q1.z*k1.z + q1.w*k1.w
                + q2.x*k2.x + q2.y*k2.y + q2.z*k2.z + q2.w*k2.w;
        score = s * SCALE_F;
        const float4* V4 = (const float4*)(V + (b * NPATCH + tid) * NQ);
        v0 = V4[0]; v1 = V4[1]; v2 = V4[2];
    }
    float m = score;
    #pragma unroll
    for (int o = 32; o > 0; o >>= 1) m = fmaxf(m, __shfl_down(m, o));
    int lane = tid & 63, wv = tid >> 6;
    if (lane == 0) redm[wv] = m;
    __syncthreads();
    float maxv = fmaxf(fmaxf(redm[0], redm[1]), fmaxf(redm[2], redm[3]));

    float w = (tid < NPATCH) ? expf(score - maxv) : 0.0f;
    float sm = w;
    #pragma unroll
    for (int o = 32; o > 0; o >>= 1) sm += __shfl_down(sm, o);
    if (lane == 0) reds[wv] = sm;

    float part[NQ];
    #pragma unroll
    for (int d = 0; d < NQ; d++) part[d] = 0.0f;
    if (tid < NPATCH) {
        part[0] = w*v0.x; part[1] = w*v0.y; part[2]  = w*v0.z; part[3]  = w*v0.w;
        part[4] = w*v1.x; part[5] = w*v1.y; part[6]  = w*v1.z; part[7]  = w*v1.w;
        part[8] = w*v2.x; part[9] = w*v2.y; part[10] = w*v2.z; part[11] = w*v2.w;
    }
    #pragma unroll
    for (int d = 0; d < NQ; d++) {
        #pragma unroll
        for (int o = 32; o > 0; o >>= 1) part[d] += __shfl_down(part[d], o);
    }
    if (lane == 0) {
        #pragma unroll
        for (int d = 0; d < NQ; d++) redv[wv][d] = part[d];
    }
    __syncthreads();
    if (tid < NQ) {
        float sumv = reds[0] + reds[1] + reds[2] + reds[3];
        float s = redv[0][tid] + redv[1][tid] + redv[2][tid] + redv[3][tid];
        outb[(size_t)b * FEATDIM + qp * NQ + tid] = s / sumv;
    }
}

// ---- Kernel: classifier -----------------------------------------------------
__global__ __launch_bounds__(256) void cls_kernel(
    const float* __restrict__ outb,   // (4,2352)
    const float* __restrict__ Wc,     // (1000,2352)
    const float* __restrict__ bc,     // (1000,)
    float* __restrict__ logits)       // (4,1000)
{
    int o = blockIdx.x, tid = threadIdx.x;
    float acc[NB] = {0.0f, 0.0f, 0.0f, 0.0f};
    const float4* w4 = (const float4*)(Wc + (size_t)o * FEATDIM);
    for (int j = tid; j < FEATDIM / 4; j += 256) {
        float4 w = w4[j];
        #pragma unroll
        for (int b = 0; b < NB; b++) {
            float4 ov = ((const float4*)(outb + (size_t)b * FEATDIM))[j];
            acc[b] += w.x*ov.x + w.y*ov.y + w.z*ov.z + w.w*ov.w;
        }
    }
    #pragma unroll
    for (int b = 0; b < NB; b++) {
        #pragma unroll
        for (int off = 32; off > 0; off >>= 1) acc[b] += __shfl_down(acc[b], off);
    }
    __shared__ float red[4][NB];
    int lane = tid & 63, wv = tid >> 6;
    if (lane == 0) {
        #pragma unroll
        for (int b = 0; b < NB; b++) red[wv][b] = acc[b];
    }
    __syncthreads();
    if (tid < NB) {
        float s = red[0][tid] + red[1][tid] + red[2][tid] + red[3][tid];
        logits[(size_t)tid * NCLS + o] = s + bc[o];
    }
}

// ---- Launch ----------------------------------------------------------------
extern "C" void kernel_launch(void* const* d_in, const int* in_sizes, int n_in,
                              void* d_out, int out_size, void* d_ws, size_t ws_size,
                              hipStream_t stream) {
    const float* x     = (const float*)d_in[0];
    const float* Wp    = (const float*)d_in[1];
    const float* bproj = (const float*)d_in[2];
    const float* qp    = (const float*)d_in[3];
    const float* kp    = (const float*)d_in[4];
    const float* vp    = (const float*)d_in[5];
    const float* Wc    = (const float*)d_in[6];
    const float* bc    = (const float*)d_in[7];
    float* logits = (float*)d_out;

    float* ws   = (float*)d_ws;
    float* qkv  = ws;                 // 3*784*12 = 28224 floats
    float* outb = ws + 28224;         // 4*2352   =  9408 floats

    qcirc_kernel<<<dim3(NPATCH, NB, 3), 128, 0, stream>>>(x, Wp, bproj, qp, kp, vp, qkv);
    attn_kernel <<<dim3(NPATCH, NB),    256, 0, stream>>>(qkv, outb);
    cls_kernel  <<<NCLS,                256, 0, stream>>>(outb, Wc, bc, logits);
}